// Round 1
// baseline (5675.241 us; speedup 1.0000x reference)
//
#include <hip/hip_runtime.h>
#include <hip/hip_bf16.h>
#include <math.h>

#define N_ROWS 32768
#define DIM 256
#define KC 2048

// workspace float offsets
#define WS_CB     0                        // codebook [K][D]
#define WS_CN     (KC*DIM)                 // cnorm [K]
#define WS_EMBSUM (WS_CN + KC)             // embed_sum [K][D]
#define WS_CNTR   (WS_EMBSUM + KC*DIM)     // countsR [K]
#define WS_CNTA   (WS_CNTR + KC)           // countsA [K]
#define WS_LOSS   (WS_CNTA + KC)           // 4 loss accumulators
#define WS_IDXR   1054976                  // int region, N ints
#define WS_IDXA   (WS_IDXR + N_ROWS)

// ---------------- codebook = emb @ proj_w^T + proj_b, plus row norms ----------
__global__ __launch_bounds__(256) void k_codebook(
    const float* __restrict__ emb, const float* __restrict__ pw,
    const float* __restrict__ pb, float* __restrict__ cb, float* __restrict__ cn)
{
  __shared__ float e[256];
  __shared__ float red[4];
  const int k = blockIdx.x, d = threadIdx.x;
  e[d] = emb[(size_t)k*DIM + d];
  __syncthreads();
  const float4* pwr = (const float4*)(pw + (size_t)d*DIM);
  const float4* e4  = (const float4*)e;
  float s0=0.f,s1=0.f,s2=0.f,s3=0.f;
#pragma unroll 8
  for (int j=0;j<64;j+=4) {
    float4 w0=pwr[j], w1=pwr[j+1], w2=pwr[j+2], w3=pwr[j+3];
    float4 a0=e4[j],  a1=e4[j+1],  a2=e4[j+2],  a3=e4[j+3];
    s0=fmaf(w0.x,a0.x,s0); s0=fmaf(w0.y,a0.y,s0); s0=fmaf(w0.z,a0.z,s0); s0=fmaf(w0.w,a0.w,s0);
    s1=fmaf(w1.x,a1.x,s1); s1=fmaf(w1.y,a1.y,s1); s1=fmaf(w1.z,a1.z,s1); s1=fmaf(w1.w,a1.w,s1);
    s2=fmaf(w2.x,a2.x,s2); s2=fmaf(w2.y,a2.y,s2); s2=fmaf(w2.z,a2.z,s2); s2=fmaf(w2.w,a2.w,s2);
    s3=fmaf(w3.x,a3.x,s3); s3=fmaf(w3.y,a3.y,s3); s3=fmaf(w3.z,a3.z,s3); s3=fmaf(w3.w,a3.w,s3);
  }
  float v = ((s0+s1)+(s2+s3)) + pb[d];
  cb[(size_t)k*DIM + d] = v;
  float sq = v*v;
#pragma unroll
  for (int off=32; off>=1; off>>=1) sq += __shfl_xor(sq, off);
  if ((d & 63) == 0) red[d>>6] = sq;
  __syncthreads();
  if (d == 0) cn[k] = (red[0]+red[1])+(red[2]+red[3]);
}

// ---------------- fused dist+softmax+argmin+softq (flash-style) --------------
// block: 256 thr = 4 waves; wave handles 16 rows; lane l: q=l>>4 owns float4
// columns {q, q+4, ..., q+60} of its row (consecutive 16B across q -> no LDS
// bank conflicts, 16-way broadcast).
__global__ __launch_bounds__(256) void k_vq(
    const float* __restrict__ XR, const float* __restrict__ XA,
    const float* __restrict__ CB, const float* __restrict__ CN,
    float* __restrict__ outR, float* __restrict__ outA,
    int* __restrict__ idxR, int* __restrict__ idxA)
{
  __shared__ float Cs[64*256];
  __shared__ float cns[64];
  const int tid = threadIdx.x;
  const int w = tid >> 6;
  const int l = tid & 63;
  const int q = l >> 4;
  const int rr = l & 15;
  const int row = blockIdx.x*64 + w*16 + rr;
  const float* __restrict__ X    = blockIdx.y ? XA   : XR;
  float* __restrict__       outq = blockIdx.y ? outA : outR;
  int* __restrict__         idxo = blockIdx.y ? idxA : idxR;

  const float4* xp = (const float4*)(X + (size_t)row*DIM);
  float4 xv[16];
#pragma unroll
  for (int j=0;j<16;j++) xv[j] = xp[4*j + q];

  float4 acc[16];
#pragma unroll
  for (int j=0;j<16;j++) acc[j] = make_float4(0.f,0.f,0.f,0.f);
  float m = -INFINITY, Z = 0.f, bestg = -INFINITY;
  int bestk = 0;

  for (int kt = 0; kt < KC; kt += 64) {
    __syncthreads();
    {
      const float4* src = (const float4*)(CB + (size_t)kt*DIM);
      float4* dst = (float4*)Cs;
#pragma unroll
      for (int i=0;i<16;i++) dst[i*256 + tid] = src[i*256 + tid];
      if (tid < 64) cns[tid] = CN[kt + tid];
    }
    __syncthreads();
    for (int k=0;k<64;k++) {
      const float4* crow = (const float4*)(Cs + k*256);
      float p0=0.f,p1=0.f,p2=0.f,p3=0.f;
#pragma unroll
      for (int j=0;j<16;j+=4) {
        float4 c0 = crow[4*j      + q];
        float4 c1 = crow[4*j + 4  + q];
        float4 c2 = crow[4*j + 8  + q];
        float4 c3 = crow[4*j + 12 + q];
        p0=fmaf(c0.x,xv[j  ].x,p0); p0=fmaf(c0.y,xv[j  ].y,p0); p0=fmaf(c0.z,xv[j  ].z,p0); p0=fmaf(c0.w,xv[j  ].w,p0);
        p1=fmaf(c1.x,xv[j+1].x,p1); p1=fmaf(c1.y,xv[j+1].y,p1); p1=fmaf(c1.z,xv[j+1].z,p1); p1=fmaf(c1.w,xv[j+1].w,p1);
        p2=fmaf(c2.x,xv[j+2].x,p2); p2=fmaf(c2.y,xv[j+2].y,p2); p2=fmaf(c2.z,xv[j+2].z,p2); p2=fmaf(c2.w,xv[j+2].w,p2);
        p3=fmaf(c3.x,xv[j+3].x,p3); p3=fmaf(c3.y,xv[j+3].y,p3); p3=fmaf(c3.z,xv[j+3].z,p3); p3=fmaf(c3.w,xv[j+3].w,p3);
      }
      float p = (p0+p1)+(p2+p3);
      p += __shfl_xor(p, 16);
      p += __shfl_xor(p, 32);
      const float g = 2.f*p - cns[k];           // argmax g == argmin dist
      if (g > bestg) { bestg = g; bestk = kt + k; }
      const float lgt = 2.f * g;                // invtemp = 1/0.5, x-norm cancels
      if (lgt > m) {                            // new running max: rescale
        const float sc = __expf(m - lgt);
        m = lgt;
        Z = fmaf(Z, sc, 1.f);
#pragma unroll
        for (int j=0;j<16;j++) {
          float4 c = crow[4*j + q];
          acc[j].x = fmaf(acc[j].x, sc, c.x);
          acc[j].y = fmaf(acc[j].y, sc, c.y);
          acc[j].z = fmaf(acc[j].z, sc, c.z);
          acc[j].w = fmaf(acc[j].w, sc, c.w);
        }
      } else {
        const float wgt = __expf(lgt - m);
        Z += wgt;
#pragma unroll
        for (int j=0;j<16;j++) {
          float4 c = crow[4*j + q];
          acc[j].x = fmaf(wgt, c.x, acc[j].x);
          acc[j].y = fmaf(wgt, c.y, acc[j].y);
          acc[j].z = fmaf(wgt, c.z, acc[j].z);
          acc[j].w = fmaf(wgt, c.w, acc[j].w);
        }
      }
    }
  }
  const float invZ = 1.f / Z;
  float4* op = (float4*)(outq + (size_t)row*DIM);
#pragma unroll
  for (int j=0;j<16;j++) {
    float4 o;
    o.x = xv[j].x + (acc[j].x*invZ - xv[j].x);  // mimic x + (softq - x)
    o.y = xv[j].y + (acc[j].y*invZ - xv[j].y);
    o.z = xv[j].z + (acc[j].z*invZ - xv[j].z);
    o.w = xv[j].w + (acc[j].w*invZ - xv[j].w);
    op[4*j + q] = o;
  }
  if (q == 0) idxo[row] = bestk;
}

// ---------------- embed_sum + counts via bucketed scan (no global atomics) ---
__global__ __launch_bounds__(256) void k_scatter(
    const float* __restrict__ XR, const float* __restrict__ XA,
    const int* __restrict__ idxR, const int* __restrict__ idxA,
    float* __restrict__ embSum, float* __restrict__ cntR, float* __restrict__ cntA)
{
  __shared__ float accw[4][8][256];   // per-wave private accumulators, 32KB
  __shared__ float cR[4][8], cA[4][8];
  const int tid = threadIdx.x;
  const int w = tid >> 6, l = tid & 63;
  const int kbase = blockIdx.x * 8;

  for (int i = tid; i < 4*8*256; i += 256) (&accw[0][0][0])[i] = 0.f;
  if (tid < 32) { cR[tid>>3][tid&7] = 0.f; cA[tid>>3][tid&7] = 0.f; }
  __syncthreads();

  for (int mod = 0; mod < 2; ++mod) {
    const int*   idx = mod ? idxA : idxR;
    const float* X   = mod ? XA   : XR;
    float* cw        = mod ? &cA[w][0] : &cR[w][0];
    for (int base = w*8192; base < (w+1)*8192; base += 64) {
      const int myidx = idx[base + l];
      const int rel = myidx - kbase;
      unsigned long long mask = __ballot(rel >= 0 && rel < 8);
      while (mask) {
        const int bit = __ffsll(mask) - 1; mask &= mask - 1;
        const int r = base + bit;
        const int code = __shfl(rel, bit);
        const float4 xr = ((const float4*)(X + (size_t)r*DIM))[l];
        float* a = &accw[w][code][l*4];
        a[0]+=xr.x; a[1]+=xr.y; a[2]+=xr.z; a[3]+=xr.w;
        if (l == 0) cw[code] += 1.f;
      }
    }
  }
  __syncthreads();
  for (int i = tid; i < 8*256; i += 256) {
    const int code = i >> 8, d = i & 255;
    const float s = (accw[0][code][d]+accw[1][code][d])+(accw[2][code][d]+accw[3][code][d]);
    embSum[(size_t)(kbase+code)*DIM + d] = s;
  }
  if (tid < 8) {
    cntR[kbase+tid] = ((cR[0][tid]+cR[1][tid])+(cR[2][tid]+cR[3][tid]));
    cntA[kbase+tid] = ((cA[0][tid]+cA[1][tid])+(cA[2][tid]+cA[3][tid]));
  }
}

// ---------------- MSE loss partial sums --------------------------------------
__device__ inline float sq4(float4 a, float4 b) {
  float dx=a.x-b.x, dy=a.y-b.y, dz=a.z-b.z, dw=a.w-b.w;
  return fmaf(dx,dx,fmaf(dy,dy,fmaf(dz,dz,dw*dw)));
}

__global__ __launch_bounds__(256) void k_loss(
    const float* __restrict__ XR, const float* __restrict__ XA,
    const float* __restrict__ CB,
    const int* __restrict__ idxR, const int* __restrict__ idxA,
    float* __restrict__ loss4)
{
  const int tid = threadIdx.x, w = tid>>6, l = tid&63;
  const int rbase = blockIdx.x*64 + w*16;
  float s0=0.f,s1=0.f,s2=0.f,s3=0.f;
  for (int t=0;t<16;t++) {
    const int r = rbase + t;
    const int iR = idxR[r], iA = idxA[r];
    const float4 xr = ((const float4*)(XR + (size_t)r*DIM))[l];
    const float4 xa = ((const float4*)(XA + (size_t)r*DIM))[l];
    const float4 cr = ((const float4*)(CB + (size_t)iR*DIM))[l];
    const float4 ca = ((const float4*)(CB + (size_t)iA*DIM))[l];
    s0 += sq4(xr,cr);   // mse(scR, hardR)
    s1 += sq4(xa,ca);   // mse(scA, hardA)
    s2 += sq4(xr,ca);   // mse(hardA, scR)
    s3 += sq4(xa,cr);   // mse(hardR, scA)
  }
#pragma unroll
  for (int off=32; off>=1; off>>=1) {
    s0 += __shfl_xor(s0, off); s1 += __shfl_xor(s1, off);
    s2 += __shfl_xor(s2, off); s3 += __shfl_xor(s3, off);
  }
  if (l == 0) {
    atomicAdd(loss4+0, s0); atomicAdd(loss4+1, s1);
    atomicAdd(loss4+2, s2); atomicAdd(loss4+3, s3);
  }
}

// ---------------- EMA update -------------------------------------------------
__global__ __launch_bounds__(256) void k_ema(
    const float* __restrict__ emaCS, const float* __restrict__ emaW,
    const float* __restrict__ embSum,
    const float* __restrict__ cntR, const float* __restrict__ cntA,
    float* __restrict__ newEmb, float* __restrict__ newCS, float* __restrict__ newEW)
{
  const int k = blockIdx.x, d = threadIdx.x;
  const float cs  = cntR[k] + cntA[k];
  const float ncs = emaCS[k]*0.99f + 0.01f*cs;
  if (d == 0) newCS[k] = ncs;
  const size_t o = (size_t)k*DIM + d;
  const float nw = emaW[o]*0.99f + 0.01f*embSum[o];
  newEW[o] = nw;
  const float dv = ncs < 1e-5f ? 1e-5f : ncs;
  newEmb[o] = nw / dv;
}

// ---------------- perplexity + final scalar losses ---------------------------
__global__ __launch_bounds__(256) void k_final(
    const float* __restrict__ cntR, const float* __restrict__ cntA,
    const float* __restrict__ loss4, float* __restrict__ outs)
{
  __shared__ float rA[256], rB[256];
  const int tid = threadIdx.x;
  float eR=0.f, eA=0.f;
  for (int k=tid; k<KC; k+=256) {
    const float aR = cntR[k] * (1.f/32768.f);
    const float aA = cntA[k] * (1.f/32768.f);
    eR = fmaf(aR, logf(aR + 1e-10f), eR);
    eA = fmaf(aA, logf(aA + 1e-10f), eA);
  }
  rA[tid]=eR; rB[tid]=eA;
  __syncthreads();
  for (int s=128; s>0; s>>=1) {
    if (tid < s) { rA[tid]+=rA[tid+s]; rB[tid]+=rB[tid+s]; }
    __syncthreads();
  }
  if (tid == 0) {
    const float inv = 1.f/8388608.f;   // 1/(N*D)
    const float mRR=loss4[0]*inv, mAA=loss4[1]*inv, mAR=loss4[2]*inv, mRA=loss4[3]*inv;
    const float fwd = ((mAA + mRR) + 0.5f*mAR) + 0.5f*mRA;
    outs[0] = 0.5f*mRR;                      // scRNA_loss = 2*CC*mRR
    outs[1] = 0.5f*mAA + 0.25f*fwd;          // scATAC_loss
    outs[2] = expf(-rA[0]);                  // perpR
    outs[3] = expf(-rB[0]);                  // perpA
  }
}

extern "C" void kernel_launch(void* const* d_in, const int* in_sizes, int n_in,
                              void* d_out, int out_size, void* d_ws, size_t ws_size,
                              hipStream_t stream) {
  const float* XR  = (const float*)d_in[0];
  const float* XA  = (const float*)d_in[1];
  const float* EMB = (const float*)d_in[2];
  const float* PW  = (const float*)d_in[3];
  const float* PB  = (const float*)d_in[4];
  const float* ECS = (const float*)d_in[5];
  const float* EW  = (const float*)d_in[6];

  float* ws  = (float*)d_ws;
  float* out = (float*)d_out;

  float* CB = ws + WS_CB;
  float* CN = ws + WS_CN;
  float* ES = ws + WS_EMBSUM;
  float* CR = ws + WS_CNTR;
  float* CA = ws + WS_CNTA;
  float* L4 = ws + WS_LOSS;
  int*   IR = (int*)(ws + WS_IDXR);
  int*   IA = (int*)(ws + WS_IDXA);

  float* outRq  = out;
  float* outAq  = out + (size_t)N_ROWS*DIM;
  float* scal   = out + 2*(size_t)N_ROWS*DIM;  // 4 scalars
  float* newEmb = scal + 4;
  float* newCS  = newEmb + (size_t)KC*DIM;
  float* newEW  = newCS + KC;

  hipMemsetAsync(L4, 0, 4*sizeof(float), stream);
  k_codebook<<<KC, 256, 0, stream>>>(EMB, PW, PB, CB, CN);
  k_vq<<<dim3(N_ROWS/64, 2), 256, 0, stream>>>(XR, XA, CB, CN, outRq, outAq, IR, IA);
  k_scatter<<<KC/8, 256, 0, stream>>>(XR, XA, IR, IA, ES, CR, CA);
  k_loss<<<N_ROWS/64, 256, 0, stream>>>(XR, XA, CB, IR, IA, L4);
  k_ema<<<KC, 256, 0, stream>>>(ECS, EW, ES, CR, CA, newEmb, newCS, newEW);
  k_final<<<1, 256, 0, stream>>>(CR, CA, L4, scal);
}

// Round 3
// 4890.585 us; speedup vs baseline: 1.1604x; 1.1604x over previous
//
#include <hip/hip_runtime.h>
#include <hip/hip_bf16.h>
#include <math.h>

#define N_ROWS 32768
#define DIM 256
#define KC 2048

// workspace float offsets
#define WS_CB     0                        // codebook [K][D]
#define WS_CN     (KC*DIM)                 // cnorm [K]
#define WS_EMBSUM (WS_CN + KC)             // embed_sum [K][D]
#define WS_CNTR   (WS_EMBSUM + KC*DIM)     // countsR [K]
#define WS_CNTA   (WS_CNTR + KC)           // countsA [K]
#define WS_LOSS   (WS_CNTA + KC)           // 4 loss accumulators
#define WS_IDXR   1054976                  // int region, N ints
#define WS_IDXA   (WS_IDXR + N_ROWS)

// ---------------- codebook = emb @ proj_w^T + proj_b, plus row norms ----------
__global__ __launch_bounds__(256) void k_codebook(
    const float* __restrict__ emb, const float* __restrict__ pw,
    const float* __restrict__ pb, float* __restrict__ cb, float* __restrict__ cn)
{
  __shared__ float e[256];
  __shared__ float red[4];
  const int k = blockIdx.x, d = threadIdx.x;
  e[d] = emb[(size_t)k*DIM + d];
  __syncthreads();
  const float4* pwr = (const float4*)(pw + (size_t)d*DIM);
  const float4* e4  = (const float4*)e;
  float s0=0.f,s1=0.f,s2=0.f,s3=0.f;
#pragma unroll 8
  for (int j=0;j<64;j+=4) {
    float4 w0=pwr[j], w1=pwr[j+1], w2=pwr[j+2], w3=pwr[j+3];
    float4 a0=e4[j],  a1=e4[j+1],  a2=e4[j+2],  a3=e4[j+3];
    s0=fmaf(w0.x,a0.x,s0); s0=fmaf(w0.y,a0.y,s0); s0=fmaf(w0.z,a0.z,s0); s0=fmaf(w0.w,a0.w,s0);
    s1=fmaf(w1.x,a1.x,s1); s1=fmaf(w1.y,a1.y,s1); s1=fmaf(w1.z,a1.z,s1); s1=fmaf(w1.w,a1.w,s1);
    s2=fmaf(w2.x,a2.x,s2); s2=fmaf(w2.y,a2.y,s2); s2=fmaf(w2.z,a2.z,s2); s2=fmaf(w2.w,a2.w,s2);
    s3=fmaf(w3.x,a3.x,s3); s3=fmaf(w3.y,a3.y,s3); s3=fmaf(w3.z,a3.z,s3); s3=fmaf(w3.w,a3.w,s3);
  }
  float v = ((s0+s1)+(s2+s3)) + pb[d];
  cb[(size_t)k*DIM + d] = v;
  float sq = v*v;
#pragma unroll
  for (int off=32; off>=1; off>>=1) sq += __shfl_xor(sq, off);
  if ((d & 63) == 0) red[d>>6] = sq;
  __syncthreads();
  if (d == 0) cn[k] = (red[0]+red[1])+(red[2]+red[3]);
}

// ---------------- fused dist+softmax+argmin+softq (scalar-broadcast) ---------
// lane = row (64 rows/block), wave = dim-quarter (64 dims).
// Codebook chunks are wave-uniform -> streamed through SGPRs (s_load), NOT LDS.
// Only the cross-wave dot reduce touches LDS (32KB, conflict-free).
__global__ __launch_bounds__(256, 2) void k_vq(
    const float* __restrict__ XR, const float* __restrict__ XA,
    const float* __restrict__ CB, const float* __restrict__ CN,
    float* __restrict__ outR, float* __restrict__ outA,
    int* __restrict__ idxR, int* __restrict__ idxA)
{
  __shared__ float dbuf[32*64*4];   // [code][row][slot] 32KB
  const int tid = threadIdx.x;
  const int l = tid & 63;                                    // row lane
  const int wq = __builtin_amdgcn_readfirstlane(tid >> 6);   // wave = dim quarter
  const int row = blockIdx.x*64 + l;
  const float* __restrict__ X    = blockIdx.y ? XA   : XR;
  float* __restrict__       outq = blockIdx.y ? outA : outR;
  int* __restrict__         idxo = blockIdx.y ? idxA : idxR;

  // x quarter in registers: 16 float4 = 64 VGPR
  const float4* xp = (const float4*)(X + (size_t)row*DIM + wq*64);
  float4 xv[16];
#pragma unroll
  for (int j=0;j<16;j++) xv[j] = xp[j];

  float4 acc4[16];
#pragma unroll
  for (int j=0;j<16;j++) acc4[j] = make_float4(0.f,0.f,0.f,0.f);

  float m = -INFINITY, Z = 0.f, bestg = -INFINITY;
  int bestk = 0;
  const int slot = wq ^ ((l>>3)&3);   // spread banks on partial-writes
  const int wrbase = l*4 + slot;

  for (int kt = 0; kt < KC; kt += 32) {
    const float* cbase = CB + (size_t)kt*DIM + wq*64;  // wave-uniform
    const float* cnp   = CN + kt;                      // wave-uniform
    float dots[32];

    // ---- partial dots over this wave's 64 dims (c chunks via SGPR) ----
#pragma unroll
    for (int c=0;c<32;c++) {
      const float4* cs = (const float4*)(cbase + c*DIM);
      float p0=0.f,p1=0.f,p2=0.f,p3=0.f;
#pragma unroll
      for (int j=0;j<16;j+=4) {
        float4 c0=cs[j], c1=cs[j+1], c2=cs[j+2], c3=cs[j+3];
        p0=fmaf(c0.x,xv[j  ].x,p0); p0=fmaf(c0.y,xv[j  ].y,p0); p0=fmaf(c0.z,xv[j  ].z,p0); p0=fmaf(c0.w,xv[j  ].w,p0);
        p1=fmaf(c1.x,xv[j+1].x,p1); p1=fmaf(c1.y,xv[j+1].y,p1); p1=fmaf(c1.z,xv[j+1].z,p1); p1=fmaf(c1.w,xv[j+1].w,p1);
        p2=fmaf(c2.x,xv[j+2].x,p2); p2=fmaf(c2.y,xv[j+2].y,p2); p2=fmaf(c2.z,xv[j+2].z,p2); p2=fmaf(c2.w,xv[j+2].w,p2);
        p3=fmaf(c3.x,xv[j+3].x,p3); p3=fmaf(c3.y,xv[j+3].y,p3); p3=fmaf(c3.z,xv[j+3].z,p3); p3=fmaf(c3.w,xv[j+3].w,p3);
      }
      dots[c] = (p0+p1)+(p2+p3);
    }

    // ---- cross-wave reduce through LDS ----
    __syncthreads();
#pragma unroll
    for (int c=0;c<32;c++) dbuf[c*256 + wrbase] = dots[c];
    __syncthreads();
#pragma unroll
    for (int c=0;c<32;c++) {
      const float4 t = ((const float4*)dbuf)[c*64 + l];   // slot-permuted, sum-invariant
      dots[c] = (t.x+t.y)+(t.z+t.w);
    }

    // ---- g = 2p - |c|^2 ; argmax ; tile-batched online softmax ----
    float tmax = -INFINITY;
#pragma unroll
    for (int c=0;c<32;c++) {
      const float gg = fmaf(2.f, dots[c], -cnp[c]);
      dots[c] = gg;
      tmax = fmaxf(tmax, gg);
    }
#pragma unroll
    for (int c=0;c<32;c++) {
      const bool b = dots[c] > bestg;
      bestg = b ? dots[c] : bestg;
      bestk = b ? kt + c : bestk;
    }
    const float nm = fmaxf(m, 2.f*tmax);    // logits = 2*g
    const float sc = __expf(m - nm);
    m = nm;
    float zs = 0.f;
#pragma unroll
    for (int c=0;c<32;c++) {
      const float wgt = __expf(fmaf(2.f, dots[c], -nm));
      dots[c] = wgt;
      zs += wgt;
    }
    Z = fmaf(Z, sc, zs);
#pragma unroll
    for (int j=0;j<16;j++) {
      acc4[j].x *= sc; acc4[j].y *= sc; acc4[j].z *= sc; acc4[j].w *= sc;
    }

    // ---- softq accumulate over this wave's 64 dims (c via SGPR again) ----
#pragma unroll
    for (int c=0;c<32;c++) {
      const float wgt = dots[c];
      const float4* cs = (const float4*)(cbase + c*DIM);
#pragma unroll
      for (int j=0;j<16;j++) {
        const float4 cv = cs[j];
        acc4[j].x = fmaf(wgt, cv.x, acc4[j].x);
        acc4[j].y = fmaf(wgt, cv.y, acc4[j].y);
        acc4[j].z = fmaf(wgt, cv.z, acc4[j].z);
        acc4[j].w = fmaf(wgt, cv.w, acc4[j].w);
      }
    }
  }

  const float invZ = 1.f / Z;
  float4* op = (float4*)(outq + (size_t)row*DIM + wq*64);
#pragma unroll
  for (int j=0;j<16;j++) {
    float4 o;
    o.x = xv[j].x + (acc4[j].x*invZ - xv[j].x);   // mimic x + (softq - x)
    o.y = xv[j].y + (acc4[j].y*invZ - xv[j].y);
    o.z = xv[j].z + (acc4[j].z*invZ - xv[j].z);
    o.w = xv[j].w + (acc4[j].w*invZ - xv[j].w);
    op[j] = o;
  }
  if (wq == 0) idxo[row] = bestk;
}

// ---------------- embed_sum + counts via bucketed scan (no global atomics) ---
__global__ __launch_bounds__(256) void k_scatter(
    const float* __restrict__ XR, const float* __restrict__ XA,
    const int* __restrict__ idxR, const int* __restrict__ idxA,
    float* __restrict__ embSum, float* __restrict__ cntR, float* __restrict__ cntA)
{
  __shared__ float accw[4][8][256];   // per-wave private accumulators, 32KB
  __shared__ float cR[4][8], cA[4][8];
  const int tid = threadIdx.x;
  const int w = tid >> 6, l = tid & 63;
  const int kbase = blockIdx.x * 8;

  for (int i = tid; i < 4*8*256; i += 256) (&accw[0][0][0])[i] = 0.f;
  if (tid < 32) { cR[tid>>3][tid&7] = 0.f; cA[tid>>3][tid&7] = 0.f; }
  __syncthreads();

  for (int mod = 0; mod < 2; ++mod) {
    const int*   idx = mod ? idxA : idxR;
    const float* X   = mod ? XA   : XR;
    float* cw        = mod ? &cA[w][0] : &cR[w][0];
    for (int base = w*8192; base < (w+1)*8192; base += 64) {
      const int myidx = idx[base + l];
      const int rel = myidx - kbase;
      unsigned long long mask = __ballot(rel >= 0 && rel < 8);
      while (mask) {
        const int bit = __ffsll(mask) - 1; mask &= mask - 1;
        const int r = base + bit;
        const int code = __shfl(rel, bit);
        const float4 xr = ((const float4*)(X + (size_t)r*DIM))[l];
        float* a = &accw[w][code][l*4];
        a[0]+=xr.x; a[1]+=xr.y; a[2]+=xr.z; a[3]+=xr.w;
        if (l == 0) cw[code] += 1.f;
      }
    }
  }
  __syncthreads();
  for (int i = tid; i < 8*256; i += 256) {
    const int code = i >> 8, d = i & 255;
    const float s = (accw[0][code][d]+accw[1][code][d])+(accw[2][code][d]+accw[3][code][d]);
    embSum[(size_t)(kbase+code)*DIM + d] = s;
  }
  if (tid < 8) {
    cntR[kbase+tid] = ((cR[0][tid]+cR[1][tid])+(cR[2][tid]+cR[3][tid]));
    cntA[kbase+tid] = ((cA[0][tid]+cA[1][tid])+(cA[2][tid]+cA[3][tid]));
  }
}

// ---------------- MSE loss partial sums --------------------------------------
__device__ inline float sq4(float4 a, float4 b) {
  float dx=a.x-b.x, dy=a.y-b.y, dz=a.z-b.z, dw=a.w-b.w;
  return fmaf(dx,dx,fmaf(dy,dy,fmaf(dz,dz,dw*dw)));
}

__global__ __launch_bounds__(256) void k_loss(
    const float* __restrict__ XR, const float* __restrict__ XA,
    const float* __restrict__ CB,
    const int* __restrict__ idxR, const int* __restrict__ idxA,
    float* __restrict__ loss4)
{
  const int tid = threadIdx.x, w = tid>>6, l = tid&63;
  const int rbase = blockIdx.x*64 + w*16;
  float s0=0.f,s1=0.f,s2=0.f,s3=0.f;
  for (int t=0;t<16;t++) {
    const int r = rbase + t;
    const int iR = idxR[r], iA = idxA[r];
    const float4 xr = ((const float4*)(XR + (size_t)r*DIM))[l];
    const float4 xa = ((const float4*)(XA + (size_t)r*DIM))[l];
    const float4 cr = ((const float4*)(CB + (size_t)iR*DIM))[l];
    const float4 ca = ((const float4*)(CB + (size_t)iA*DIM))[l];
    s0 += sq4(xr,cr);   // mse(scR, hardR)
    s1 += sq4(xa,ca);   // mse(scA, hardA)
    s2 += sq4(xr,ca);   // mse(hardA, scR)
    s3 += sq4(xa,cr);   // mse(hardR, scA)
  }
#pragma unroll
  for (int off=32; off>=1; off>>=1) {
    s0 += __shfl_xor(s0, off); s1 += __shfl_xor(s1, off);
    s2 += __shfl_xor(s2, off); s3 += __shfl_xor(s3, off);
  }
  if (l == 0) {
    atomicAdd(loss4+0, s0); atomicAdd(loss4+1, s1);
    atomicAdd(loss4+2, s2); atomicAdd(loss4+3, s3);
  }
}

// ---------------- EMA update -------------------------------------------------
__global__ __launch_bounds__(256) void k_ema(
    const float* __restrict__ emaCS, const float* __restrict__ emaW,
    const float* __restrict__ embSum,
    const float* __restrict__ cntR, const float* __restrict__ cntA,
    float* __restrict__ newEmb, float* __restrict__ newCS, float* __restrict__ newEW)
{
  const int k = blockIdx.x, d = threadIdx.x;
  const float cs  = cntR[k] + cntA[k];
  const float ncs = emaCS[k]*0.99f + 0.01f*cs;
  if (d == 0) newCS[k] = ncs;
  const size_t o = (size_t)k*DIM + d;
  const float nw = emaW[o]*0.99f + 0.01f*embSum[o];
  newEW[o] = nw;
  const float dv = ncs < 1e-5f ? 1e-5f : ncs;
  newEmb[o] = nw / dv;
}

// ---------------- perplexity + final scalar losses ---------------------------
__global__ __launch_bounds__(256) void k_final(
    const float* __restrict__ cntR, const float* __restrict__ cntA,
    const float* __restrict__ loss4, float* __restrict__ outs)
{
  __shared__ float rA[256], rB[256];
  const int tid = threadIdx.x;
  float eR=0.f, eA=0.f;
  for (int k=tid; k<KC; k+=256) {
    const float aR = cntR[k] * (1.f/32768.f);
    const float aA = cntA[k] * (1.f/32768.f);
    eR = fmaf(aR, logf(aR + 1e-10f), eR);
    eA = fmaf(aA, logf(aA + 1e-10f), eA);
  }
  rA[tid]=eR; rB[tid]=eA;
  __syncthreads();
  for (int s=128; s>0; s>>=1) {
    if (tid < s) { rA[tid]+=rA[tid+s]; rB[tid]+=rB[tid+s]; }
    __syncthreads();
  }
  if (tid == 0) {
    const float inv = 1.f/8388608.f;   // 1/(N*D)
    const float mRR=loss4[0]*inv, mAA=loss4[1]*inv, mAR=loss4[2]*inv, mRA=loss4[3]*inv;
    const float fwd = ((mAA + mRR) + 0.5f*mAR) + 0.5f*mRA;
    outs[0] = 0.5f*mRR;                      // scRNA_loss = 2*CC*mRR
    outs[1] = 0.5f*mAA + 0.25f*fwd;          // scATAC_loss
    outs[2] = expf(-rA[0]);                  // perpR
    outs[3] = expf(-rB[0]);                  // perpA
  }
}

extern "C" void kernel_launch(void* const* d_in, const int* in_sizes, int n_in,
                              void* d_out, int out_size, void* d_ws, size_t ws_size,
                              hipStream_t stream) {
  const float* XR  = (const float*)d_in[0];
  const float* XA  = (const float*)d_in[1];
  const float* EMB = (const float*)d_in[2];
  const float* PW  = (const float*)d_in[3];
  const float* PB  = (const float*)d_in[4];
  const float* ECS = (const float*)d_in[5];
  const float* EW  = (const float*)d_in[6];

  float* ws  = (float*)d_ws;
  float* out = (float*)d_out;

  float* CB = ws + WS_CB;
  float* CN = ws + WS_CN;
  float* ES = ws + WS_EMBSUM;
  float* CR = ws + WS_CNTR;
  float* CA = ws + WS_CNTA;
  float* L4 = ws + WS_LOSS;
  int*   IR = (int*)(ws + WS_IDXR);
  int*   IA = (int*)(ws + WS_IDXA);

  float* outRq  = out;
  float* outAq  = out + (size_t)N_ROWS*DIM;
  float* scal   = out + 2*(size_t)N_ROWS*DIM;  // 4 scalars
  float* newEmb = scal + 4;
  float* newCS  = newEmb + (size_t)KC*DIM;
  float* newEW  = newCS + KC;

  hipMemsetAsync(L4, 0, 4*sizeof(float), stream);
  k_codebook<<<KC, 256, 0, stream>>>(EMB, PW, PB, CB, CN);
  k_vq<<<dim3(N_ROWS/64, 2), 256, 0, stream>>>(XR, XA, CB, CN, outRq, outAq, IR, IA);
  k_scatter<<<KC/8, 256, 0, stream>>>(XR, XA, IR, IA, ES, CR, CA);
  k_loss<<<N_ROWS/64, 256, 0, stream>>>(XR, XA, CB, IR, IA, L4);
  k_ema<<<KC, 256, 0, stream>>>(ECS, EW, ES, CR, CA, newEmb, newCS, newEW);
  k_final<<<1, 256, 0, stream>>>(CR, CA, L4, scal);
}

// Round 4
// 1312.563 us; speedup vs baseline: 4.3238x; 3.7260x over previous
//
#include <hip/hip_runtime.h>
#include <math.h>

#define N_ROWS 32768
#define DIM 256
#define KC 2048
#define CHUNK 8192
#define KBIG 768   // concat K: [Xh | Xl | Xh] x [Ch | Ch | Cl]

typedef short s16x8 __attribute__((ext_vector_type(8)));
typedef float f32x4 __attribute__((ext_vector_type(4)));

// workspace byte offsets
#define OFF_CB   0u          // f32 [2048][256] codebook
#define OFF_CN   2097152u    // f32 [2048] |c|^2
#define OFF_ES   2105344u    // f32 [2048][256] embed_sum
#define OFF_CR   4202496u    // f32 [2048]
#define OFF_CA   4210688u    // f32 [2048]
#define OFF_L4   4218880u    // f32 [4] loss acc
#define OFF_MR   4219136u    // f32 [8192] row max-logit (chunk)
#define OFF_ZI   4251904u    // f32 [8192] 1/Z (chunk)
#define OFF_IR   4284672u    // i32 [32768]
#define OFF_IA   4415744u    // i32 [32768]
#define OFF_CBB  4546816u    // bf16 [2048][768]
#define OFF_CTG  7692544u    // bf16 [256][2048]  (Ch transposed)
#define OFF_A2   8741120u    // bf16 [8192][768]  (chunk)
#define OFF_SCH  21324032u   // f32 [8192][2048]  (chunk scores)

__device__ __forceinline__ unsigned short f2bf(float f) {
  unsigned int b = __float_as_uint(f);
  b = b + 0x7FFFu + ((b >> 16) & 1u);
  return (unsigned short)(b >> 16);
}
__device__ __forceinline__ float bf2f(unsigned short u) {
  return __uint_as_float(((unsigned int)u) << 16);
}

// ---------------- codebook = emb @ proj_w^T + proj_b; norms; bf16 splits -----
__global__ __launch_bounds__(256) void k_codebook(
    const float* __restrict__ emb, const float* __restrict__ pw,
    const float* __restrict__ pb, float* __restrict__ cb, float* __restrict__ cn,
    unsigned short* __restrict__ cbb, unsigned short* __restrict__ ctg)
{
  __shared__ float e[256];
  __shared__ float red[4];
  const int k = blockIdx.x, d = threadIdx.x;
  e[d] = emb[(size_t)k*DIM + d];
  __syncthreads();
  const float4* pwr = (const float4*)(pw + (size_t)d*DIM);
  const float4* e4  = (const float4*)e;
  float s0=0.f,s1=0.f,s2=0.f,s3=0.f;
#pragma unroll 8
  for (int j=0;j<64;j+=4) {
    float4 w0=pwr[j], w1=pwr[j+1], w2=pwr[j+2], w3=pwr[j+3];
    float4 a0=e4[j],  a1=e4[j+1],  a2=e4[j+2],  a3=e4[j+3];
    s0=fmaf(w0.x,a0.x,s0); s0=fmaf(w0.y,a0.y,s0); s0=fmaf(w0.z,a0.z,s0); s0=fmaf(w0.w,a0.w,s0);
    s1=fmaf(w1.x,a1.x,s1); s1=fmaf(w1.y,a1.y,s1); s1=fmaf(w1.z,a1.z,s1); s1=fmaf(w1.w,a1.w,s1);
    s2=fmaf(w2.x,a2.x,s2); s2=fmaf(w2.y,a2.y,s2); s2=fmaf(w2.z,a2.z,s2); s2=fmaf(w2.w,a2.w,s2);
    s3=fmaf(w3.x,a3.x,s3); s3=fmaf(w3.y,a3.y,s3); s3=fmaf(w3.z,a3.z,s3); s3=fmaf(w3.w,a3.w,s3);
  }
  float v = ((s0+s1)+(s2+s3)) + pb[d];
  cb[(size_t)k*DIM + d] = v;
  unsigned short ch = f2bf(v);
  unsigned short cl = f2bf(v - bf2f(ch));
  cbb[(size_t)k*KBIG + d]       = ch;
  cbb[(size_t)k*KBIG + 256 + d] = ch;
  cbb[(size_t)k*KBIG + 512 + d] = cl;
  ctg[(size_t)d*KC + k] = ch;
  float sq = v*v;
#pragma unroll
  for (int off=32; off>=1; off>>=1) sq += __shfl_xor(sq, off);
  if ((d & 63) == 0) red[d>>6] = sq;
  __syncthreads();
  if (d == 0) cn[k] = (red[0]+red[1])+(red[2]+red[3]);
}

// ---------------- X chunk -> A2 = [Xh | Xl | Xh] bf16 ------------------------
__global__ __launch_bounds__(256) void k_splitx(
    const float* __restrict__ X, unsigned short* __restrict__ a2, int base)
{
  const int id = blockIdx.x*256 + threadIdx.x;        // 8192*64 units
  const int row = id >> 6;
  const int c4 = id & 63;
  const float4 x = ((const float4*)(X + (size_t)(base+row)*DIM))[c4];
  ushort4 h, lo;
  h.x = f2bf(x.x); lo.x = f2bf(x.x - bf2f(h.x));
  h.y = f2bf(x.y); lo.y = f2bf(x.y - bf2f(h.y));
  h.z = f2bf(x.z); lo.z = f2bf(x.z - bf2f(h.z));
  h.w = f2bf(x.w); lo.w = f2bf(x.w - bf2f(h.w));
  unsigned short* r = a2 + (size_t)row*KBIG + c4*4;
  *(ushort4*)(r)       = h;
  *(ushort4*)(r + 256) = lo;
  *(ushort4*)(r + 512) = h;
}

// ---------------- S = A2 @ CBB^T  (128x128 tile, bf16 MFMA) ------------------
__global__ __launch_bounds__(256) void k_qk(
    const unsigned short* __restrict__ a2, const unsigned short* __restrict__ b2,
    float* __restrict__ S)
{
  __shared__ short Asm[128*64];   // 16KB, XOR-swizzled slots
  __shared__ short Bsm[128*64];
  const int tid = threadIdx.x;
  const int w = tid >> 6, l = tid & 63;
  const int wr = w >> 1, wc = w & 1;
  const int rowbase = blockIdx.x * 128;
  const int colbase = blockIdx.y * 128;
  const int srow = tid >> 1, shalf = tid & 1;  // staging: 32 bf16 per thread

  f32x4 acc[4][4];
#pragma unroll
  for (int i=0;i<4;i++)
#pragma unroll
    for (int j=0;j<4;j++) acc[i][j] = (f32x4)0.f;

  for (int kb = 0; kb < KBIG; kb += 64) {
    __syncthreads();
    {
      const int4* ap = (const int4*)(a2 + (size_t)(rowbase+srow)*KBIG + kb + shalf*32);
      int4 a0=ap[0], a1=ap[1], a2v=ap[2], a3=ap[3];
      const int4* bp = (const int4*)(b2 + (size_t)(colbase+srow)*KBIG + kb + shalf*32);
      int4 b0=bp[0], b1=bp[1], b2v=bp[2], b3=bp[3];
      char* pa = (char*)Asm + srow*128;
      char* pb = (char*)Bsm + srow*128;
      const int sw = srow & 7, s0 = shalf*4;
      *(int4*)(pa + (((s0+0)^sw)<<4)) = a0;
      *(int4*)(pa + (((s0+1)^sw)<<4)) = a1;
      *(int4*)(pa + (((s0+2)^sw)<<4)) = a2v;
      *(int4*)(pa + (((s0+3)^sw)<<4)) = a3;
      *(int4*)(pb + (((s0+0)^sw)<<4)) = b0;
      *(int4*)(pb + (((s0+1)^sw)<<4)) = b1;
      *(int4*)(pb + (((s0+2)^sw)<<4)) = b2v;
      *(int4*)(pb + (((s0+3)^sw)<<4)) = b3;
    }
    __syncthreads();
#pragma unroll
    for (int ks=0; ks<2; ks++) {
      s16x8 af[4], bf[4];
      const int slot = ks*4 + (l>>4);
#pragma unroll
      for (int i=0;i<4;i++) {
        const int ra = 64*wr + 16*i + (l&15);
        af[i] = *(const s16x8*)((const char*)Asm + ra*128 + ((slot ^ (ra&7))<<4));
        const int rb = 64*wc + 16*i + (l&15);
        bf[i] = *(const s16x8*)((const char*)Bsm + rb*128 + ((slot ^ (rb&7))<<4));
      }
#pragma unroll
      for (int i=0;i<4;i++)
#pragma unroll
        for (int j=0;j<4;j++)
          acc[i][j] = __builtin_amdgcn_mfma_f32_16x16x32_bf16(af[i], bf[j], acc[i][j], 0,0,0);
    }
  }
#pragma unroll
  for (int i=0;i<4;i++)
#pragma unroll
    for (int j=0;j<4;j++)
#pragma unroll
      for (int r=0;r<4;r++) {
        const int row = 64*wr + 16*i + (l>>4)*4 + r;
        const int col = 64*wc + 16*j + (l&15);
        S[(size_t)(rowbase+row)*KC + colbase + col] = acc[i][j][r];
      }
}

// ---------------- row stats: max-logit, 1/Z, argmin --------------------------
__global__ __launch_bounds__(256) void k_b1(
    const float* __restrict__ S, const float* __restrict__ CN,
    float* __restrict__ MR, float* __restrict__ ZI, int* __restrict__ idxo,
    int rowbase0)
{
  const int tid = threadIdx.x, w = tid>>6, l = tid&63;
  for (int rr=0; rr<8; rr++) {
    const int row = blockIdx.x*32 + w*8 + rr;
    const float4* sp = (const float4*)(S + (size_t)row*KC + l*32);
    const float4* cp = (const float4*)(CN + l*32);
    float m=-INFINITY, Z=0.f, bg=-INFINITY; int bi=0;
#pragma unroll
    for (int c8=0;c8<8;c8++) {
      const float4 s4 = sp[c8], c4 = cp[c8];
      const float lg0 = 4.f*s4.x - 2.f*c4.x;
      const float lg1 = 4.f*s4.y - 2.f*c4.y;
      const float lg2 = 4.f*s4.z - 2.f*c4.z;
      const float lg3 = 4.f*s4.w - 2.f*c4.w;
      const int ib = l*32 + c8*4;
      if (lg0 > bg){bg=lg0; bi=ib;}
      if (lg1 > bg){bg=lg1; bi=ib+1;}
      if (lg2 > bg){bg=lg2; bi=ib+2;}
      if (lg3 > bg){bg=lg3; bi=ib+3;}
      float tm = fmaxf(fmaxf(lg0,lg1), fmaxf(lg2,lg3));
      if (tm > m) { Z *= __expf(m - tm); m = tm; }
      Z += __expf(lg0-m) + __expf(lg1-m) + __expf(lg2-m) + __expf(lg3-m);
    }
#pragma unroll
    for (int off=1; off<64; off<<=1) {
      const float mo = __shfl_xor(m, off), Zo = __shfl_xor(Z, off);
      const float bgo = __shfl_xor(bg, off); const int bio = __shfl_xor(bi, off);
      const float nm = fmaxf(m, mo);
      Z = Z*__expf(m-nm) + Zo*__expf(mo-nm);
      m = nm;
      if (bgo > bg || (bgo == bg && bio < bi)) { bg = bgo; bi = bio; }
    }
    if (l == 0) { MR[row] = m; ZI[row] = 1.f/Z; idxo[rowbase0+row] = bi; }
  }
}

// ---------------- O = softmax(S) @ C  (P computed in staging) ----------------
__global__ __launch_bounds__(256) void k_b2(
    const float* __restrict__ S, const float* __restrict__ CN,
    const unsigned short* __restrict__ ctg, const float* __restrict__ MR,
    const float* __restrict__ ZI, float* __restrict__ outq, int rowbase0)
{
  __shared__ short Psm[64*64];    // 8KB
  __shared__ short Csm[128*64];   // 16KB
  const int tid = threadIdx.x;
  const int w = tid >> 6, l = tid & 63;
  const int wr = w >> 1, wc = w & 1;
  const int rowb = blockIdx.x * 64;
  const int dimb = blockIdx.y * 128;
  const int prow = tid >> 2, pq = tid & 3;   // P staging: 16 codes/thread
  const int cdim = tid >> 1, chf = tid & 1;  // CT staging: 32 codes/thread
  const float mrow = MR[rowb + prow];

  f32x4 acc[2][4];
#pragma unroll
  for (int i=0;i<2;i++)
#pragma unroll
    for (int j=0;j<4;j++) acc[i][j] = (f32x4)0.f;

  for (int kb = 0; kb < KC; kb += 64) {
    __syncthreads();
    {
      const float4* sp  = (const float4*)(S  + (size_t)(rowb+prow)*KC + kb + pq*16);
      const float4* cnp = (const float4*)(CN + kb + pq*16);
      unsigned int pk[8];
#pragma unroll
      for (int g=0; g<4; g++) {
        const float4 s4 = sp[g], c4 = cnp[g];
        const float p0 = __expf(4.f*s4.x - 2.f*c4.x - mrow);
        const float p1 = __expf(4.f*s4.y - 2.f*c4.y - mrow);
        const float p2 = __expf(4.f*s4.z - 2.f*c4.z - mrow);
        const float p3 = __expf(4.f*s4.w - 2.f*c4.w - mrow);
        pk[g*2]   = (unsigned)f2bf(p0) | ((unsigned)f2bf(p1) << 16);
        pk[g*2+1] = (unsigned)f2bf(p2) | ((unsigned)f2bf(p3) << 16);
      }
      char* pb = (char*)Psm + prow*128;
      const int psw = prow & 7;
      int4 v0; v0.x=(int)pk[0]; v0.y=(int)pk[1]; v0.z=(int)pk[2]; v0.w=(int)pk[3];
      int4 v1; v1.x=(int)pk[4]; v1.y=(int)pk[5]; v1.z=(int)pk[6]; v1.w=(int)pk[7];
      *(int4*)(pb + (((pq*2+0)^psw)<<4)) = v0;
      *(int4*)(pb + (((pq*2+1)^psw)<<4)) = v1;

      const int4* ctp = (const int4*)(ctg + (size_t)(dimb+cdim)*KC + kb + chf*32);
      int4 c0=ctp[0], c1=ctp[1], c2=ctp[2], c3=ctp[3];
      char* cb_ = (char*)Csm + cdim*128;
      const int csw = cdim & 7, s0 = chf*4;
      *(int4*)(cb_ + (((s0+0)^csw)<<4)) = c0;
      *(int4*)(cb_ + (((s0+1)^csw)<<4)) = c1;
      *(int4*)(cb_ + (((s0+2)^csw)<<4)) = c2;
      *(int4*)(cb_ + (((s0+3)^csw)<<4)) = c3;
    }
    __syncthreads();
#pragma unroll
    for (int ks=0; ks<2; ks++) {
      s16x8 pa[2], cc[4];
      const int slot = ks*4 + (l>>4);
#pragma unroll
      for (int i=0;i<2;i++) {
        const int ra = 32*wr + 16*i + (l&15);
        pa[i] = *(const s16x8*)((const char*)Psm + ra*128 + ((slot ^ (ra&7))<<4));
      }
#pragma unroll
      for (int j=0;j<4;j++) {
        const int rd = 64*wc + 16*j + (l&15);
        cc[j] = *(const s16x8*)((const char*)Csm + rd*128 + ((slot ^ (rd&7))<<4));
      }
#pragma unroll
      for (int i=0;i<2;i++)
#pragma unroll
        for (int j=0;j<4;j++)
          acc[i][j] = __builtin_amdgcn_mfma_f32_16x16x32_bf16(pa[i], cc[j], acc[i][j], 0,0,0);
    }
  }
#pragma unroll
  for (int i=0;i<2;i++)
#pragma unroll
    for (int j=0;j<4;j++)
#pragma unroll
      for (int r=0;r<4;r++) {
        const int rl = 32*wr + 16*i + (l>>4)*4 + r;
        const int dg = dimb + 64*wc + 16*j + (l&15);
        outq[(size_t)(rowbase0 + rowb + rl)*DIM + dg] = acc[i][j][r] * ZI[rowb + rl];
      }
}

// ---------------- embed_sum + counts via bucketed scan -----------------------
__global__ __launch_bounds__(256) void k_scatter(
    const float* __restrict__ XR, const float* __restrict__ XA,
    const int* __restrict__ idxR, const int* __restrict__ idxA,
    float* __restrict__ embSum, float* __restrict__ cntR, float* __restrict__ cntA)
{
  __shared__ float accw[4][8][256];
  __shared__ float cR[4][8], cA[4][8];
  const int tid = threadIdx.x;
  const int w = tid >> 6, l = tid & 63;
  const int kbase = blockIdx.x * 8;

  for (int i = tid; i < 4*8*256; i += 256) (&accw[0][0][0])[i] = 0.f;
  if (tid < 32) { cR[tid>>3][tid&7] = 0.f; cA[tid>>3][tid&7] = 0.f; }
  __syncthreads();

  for (int mod = 0; mod < 2; ++mod) {
    const int*   idx = mod ? idxA : idxR;
    const float* X   = mod ? XA   : XR;
    float* cw        = mod ? &cA[w][0] : &cR[w][0];
    for (int base = w*8192; base < (w+1)*8192; base += 64) {
      const int myidx = idx[base + l];
      const int rel = myidx - kbase;
      unsigned long long mask = __ballot(rel >= 0 && rel < 8);
      while (mask) {
        const int bit = __ffsll(mask) - 1; mask &= mask - 1;
        const int r = base + bit;
        const int code = __shfl(rel, bit);
        const float4 xr = ((const float4*)(X + (size_t)r*DIM))[l];
        float* a = &accw[w][code][l*4];
        a[0]+=xr.x; a[1]+=xr.y; a[2]+=xr.z; a[3]+=xr.w;
        if (l == 0) cw[code] += 1.f;
      }
    }
  }
  __syncthreads();
  for (int i = tid; i < 8*256; i += 256) {
    const int code = i >> 8, d = i & 255;
    const float s = (accw[0][code][d]+accw[1][code][d])+(accw[2][code][d]+accw[3][code][d]);
    embSum[(size_t)(kbase+code)*DIM + d] = s;
  }
  if (tid < 8) {
    cntR[kbase+tid] = ((cR[0][tid]+cR[1][tid])+(cR[2][tid]+cR[3][tid]));
    cntA[kbase+tid] = ((cA[0][tid]+cA[1][tid])+(cA[2][tid]+cA[3][tid]));
  }
}

// ---------------- MSE loss partial sums --------------------------------------
__device__ inline float sq4(float4 a, float4 b) {
  float dx=a.x-b.x, dy=a.y-b.y, dz=a.z-b.z, dw=a.w-b.w;
  return fmaf(dx,dx,fmaf(dy,dy,fmaf(dz,dz,dw*dw)));
}

__global__ __launch_bounds__(256) void k_loss(
    const float* __restrict__ XR, const float* __restrict__ XA,
    const float* __restrict__ CB,
    const int* __restrict__ idxR, const int* __restrict__ idxA,
    float* __restrict__ loss4)
{
  const int tid = threadIdx.x, w = tid>>6, l = tid&63;
  const int rbase = blockIdx.x*64 + w*16;
  float s0=0.f,s1=0.f,s2=0.f,s3=0.f;
  for (int t=0;t<16;t++) {
    const int r = rbase + t;
    const int iR = idxR[r], iA = idxA[r];
    const float4 xr = ((const float4*)(XR + (size_t)r*DIM))[l];
    const float4 xa = ((const float4*)(XA + (size_t)r*DIM))[l];
    const float4 cr = ((const float4*)(CB + (size_t)iR*DIM))[l];
    const float4 ca = ((const float4*)(CB + (size_t)iA*DIM))[l];
    s0 += sq4(xr,cr);
    s1 += sq4(xa,ca);
    s2 += sq4(xr,ca);
    s3 += sq4(xa,cr);
  }
#pragma unroll
  for (int off=32; off>=1; off>>=1) {
    s0 += __shfl_xor(s0, off); s1 += __shfl_xor(s1, off);
    s2 += __shfl_xor(s2, off); s3 += __shfl_xor(s3, off);
  }
  if (l == 0) {
    atomicAdd(loss4+0, s0); atomicAdd(loss4+1, s1);
    atomicAdd(loss4+2, s2); atomicAdd(loss4+3, s3);
  }
}

// ---------------- EMA update -------------------------------------------------
__global__ __launch_bounds__(256) void k_ema(
    const float* __restrict__ emaCS, const float* __restrict__ emaW,
    const float* __restrict__ embSum,
    const float* __restrict__ cntR, const float* __restrict__ cntA,
    float* __restrict__ newEmb, float* __restrict__ newCS, float* __restrict__ newEW)
{
  const int k = blockIdx.x, d = threadIdx.x;
  const float cs  = cntR[k] + cntA[k];
  const float ncs = emaCS[k]*0.99f + 0.01f*cs;
  if (d == 0) newCS[k] = ncs;
  const size_t o = (size_t)k*DIM + d;
  const float nw = emaW[o]*0.99f + 0.01f*embSum[o];
  newEW[o] = nw;
  const float dv = ncs < 1e-5f ? 1e-5f : ncs;
  newEmb[o] = nw / dv;
}

// ---------------- perplexity + final scalar losses ---------------------------
__global__ __launch_bounds__(256) void k_final(
    const float* __restrict__ cntR, const float* __restrict__ cntA,
    const float* __restrict__ loss4, float* __restrict__ outs)
{
  __shared__ float rA[256], rB[256];
  const int tid = threadIdx.x;
  float eR=0.f, eA=0.f;
  for (int k=tid; k<KC; k+=256) {
    const float aR = cntR[k] * (1.f/32768.f);
    const float aA = cntA[k] * (1.f/32768.f);
    eR = fmaf(aR, logf(aR + 1e-10f), eR);
    eA = fmaf(aA, logf(aA + 1e-10f), eA);
  }
  rA[tid]=eR; rB[tid]=eA;
  __syncthreads();
  for (int s=128; s>0; s>>=1) {
    if (tid < s) { rA[tid]+=rA[tid+s]; rB[tid]+=rB[tid+s]; }
    __syncthreads();
  }
  if (tid == 0) {
    const float inv = 1.f/8388608.f;
    const float mRR=loss4[0]*inv, mAA=loss4[1]*inv, mAR=loss4[2]*inv, mRA=loss4[3]*inv;
    const float fwd = ((mAA + mRR) + 0.5f*mAR) + 0.5f*mRA;
    outs[0] = 0.5f*mRR;
    outs[1] = 0.5f*mAA + 0.25f*fwd;
    outs[2] = expf(-rA[0]);
    outs[3] = expf(-rB[0]);
  }
}

extern "C" void kernel_launch(void* const* d_in, const int* in_sizes, int n_in,
                              void* d_out, int out_size, void* d_ws, size_t ws_size,
                              hipStream_t stream) {
  const float* XR  = (const float*)d_in[0];
  const float* XA  = (const float*)d_in[1];
  const float* EMB = (const float*)d_in[2];
  const float* PW  = (const float*)d_in[3];
  const float* PB  = (const float*)d_in[4];
  const float* ECS = (const float*)d_in[5];
  const float* EW  = (const float*)d_in[6];

  char* wsb = (char*)d_ws;
  float* CB = (float*)(wsb + OFF_CB);
  float* CN = (float*)(wsb + OFF_CN);
  float* ES = (float*)(wsb + OFF_ES);
  float* CR = (float*)(wsb + OFF_CR);
  float* CA = (float*)(wsb + OFF_CA);
  float* L4 = (float*)(wsb + OFF_L4);
  float* MR = (float*)(wsb + OFF_MR);
  float* ZI = (float*)(wsb + OFF_ZI);
  int*   IR = (int*)(wsb + OFF_IR);
  int*   IA = (int*)(wsb + OFF_IA);
  unsigned short* CBB = (unsigned short*)(wsb + OFF_CBB);
  unsigned short* CTG = (unsigned short*)(wsb + OFF_CTG);
  unsigned short* A2  = (unsigned short*)(wsb + OFF_A2);
  float* SCH = (float*)(wsb + OFF_SCH);

  float* out = (float*)d_out;
  float* outRq  = out;
  float* outAq  = out + (size_t)N_ROWS*DIM;
  float* scal   = out + 2*(size_t)N_ROWS*DIM;
  float* newEmb = scal + 4;
  float* newCS  = newEmb + (size_t)KC*DIM;
  float* newEW  = newCS + KC;

  hipMemsetAsync(L4, 0, 4*sizeof(float), stream);
  k_codebook<<<KC, 256, 0, stream>>>(EMB, PW, PB, CB, CN, CBB, CTG);

  for (int it = 0; it < 8; ++it) {
    const int mod = it >> 2, cidx = it & 3;
    const float* X = mod ? XA : XR;
    float* outq    = mod ? outAq : outRq;
    int* idxo      = mod ? IA : IR;
    const int base = cidx * CHUNK;
    k_splitx<<<CHUNK*64/256, 256, 0, stream>>>(X, A2, base);
    k_qk<<<dim3(CHUNK/128, KC/128), 256, 0, stream>>>(A2, CBB, SCH);
    k_b1<<<CHUNK/32, 256, 0, stream>>>(SCH, CN, MR, ZI, idxo, base);
    k_b2<<<dim3(CHUNK/64, 2), 256, 0, stream>>>(SCH, CN, CTG, MR, ZI, outq, base);
  }

  k_scatter<<<KC/8, 256, 0, stream>>>(XR, XA, IR, IA, ES, CR, CA);
  k_loss<<<N_ROWS/64, 256, 0, stream>>>(XR, XA, CB, IR, IA, L4);
  k_ema<<<KC, 256, 0, stream>>>(ECS, EW, ES, CR, CA, newEmb, newCS, newEW);
  k_final<<<1, 256, 0, stream>>>(CR, CA, L4, scal);
}